// Round 4
// baseline (529.795 us; speedup 1.0000x reference)
//
#include <hip/hip_runtime.h>
#include <hip/hip_bf16.h>

// Problem constants (fixed by reference)
#define IN_F   4096
#define OUT_F  4096
#define RANK   16
#define M_TOK  8192          // 4 * 2048 tokens
#define SCALING 2.0f         // ALPHA / RANK = 32/16

typedef __attribute__((ext_vector_type(8))) short short8;   // 8 bf16 = 4 VGPRs
typedef __attribute__((ext_vector_type(4))) float f32x4;
typedef __attribute__((ext_vector_type(4))) float fvec4;
typedef __attribute__((ext_vector_type(4))) int   ivec4;
typedef __attribute__((ext_vector_type(4))) unsigned int uvec4;

// ---------------------------------------------------------------------------
// dequant + LoRA fold: W'[o,i] = (q-8)*scale + 2*(lB@lA)[o,i].
// Each thread owns 4 columns; lA[0:16][c0:c0+4] slice lives in 16 fvec4
// registers; 8 o-rows per block with all 8 q-loads hoisted (MLP).
// 2048 blocks x 256 threads.  96 MB HBM -> ~20 us roofline.
// ---------------------------------------------------------------------------
__global__ __launch_bounds__(256) void dequant_lora(const int* __restrict__ q,
                                                    const float* __restrict__ sc,
                                                    const float* __restrict__ lA,
                                                    const float* __restrict__ lB,
                                                    __hip_bfloat16* __restrict__ W) {
    const int tid = threadIdx.x;
    const int id  = blockIdx.x;              // 0..2047
    const int c0  = (id & 3) * 1024 + tid * 4;
    const int o0  = (id >> 2) * 8;

    ivec4 qv[8];
#pragma unroll
    for (int oo = 0; oo < 8; ++oo)           // all 8 HBM loads in flight
        qv[oo] = __builtin_nontemporal_load(
            (const ivec4*)(q + (size_t)(o0 + oo) * IN_F + c0));

    float sv[8];
#pragma unroll
    for (int oo = 0; oo < 8; ++oo)
        sv[oo] = sc[(o0 + oo) * (IN_F / 64) + (c0 >> 6)];

    fvec4 a[RANK];
#pragma unroll
    for (int r = 0; r < RANK; ++r)           // L2-resident after first touch
        a[r] = *(const fvec4*)(lA + (size_t)r * IN_F + c0);

#pragma unroll
    for (int oo = 0; oo < 8; ++oo) {
        const float* lbo = lB + (size_t)(o0 + oo) * RANK;   // uniform -> SMEM
        float l0 = 0.f, l1 = 0.f, l2 = 0.f, l3 = 0.f;
#pragma unroll
        for (int r = 0; r < RANK; ++r) {
            const float br = lbo[r];
            l0 += br * a[r].x; l1 += br * a[r].y;
            l2 += br * a[r].z; l3 += br * a[r].w;
        }
        const float s = sv[oo];
        union { ushort4 u; __hip_bfloat16 h[4]; } p;
        p.h[0] = __float2bfloat16((float)(qv[oo].x - 8) * s + SCALING * l0);
        p.h[1] = __float2bfloat16((float)(qv[oo].y - 8) * s + SCALING * l1);
        p.h[2] = __float2bfloat16((float)(qv[oo].z - 8) * s + SCALING * l2);
        p.h[3] = __float2bfloat16((float)(qv[oo].w - 8) * s + SCALING * l3);
        *(ushort4*)(W + (size_t)(o0 + oo) * IN_F + c0) = p.u;  // normal store
    }
}

// ---------------------------------------------------------------------------
// GEMM: C[M,N] = X[M,K](fp32, cvt on the fly) * B[N,K]^T(bf16) + bias
// 256x256 tile, BK=64, 512 threads = 8 waves (2M x 4N), 8-phase schedule with
// counted vmcnt (T3+T4), st_16x32 LDS swizzle (T2), setprio (T5), XCD 8x8
// chunk (T1).  Sync structure identical to the verified round-1..3 kernel.
//
// NEW this round: A is staged from fp32 x directly (xb intermediate removed).
// Reg-stage path (T14 async split): ph0/ph1 issue 8 dwordx4 loads of
// A(t+1) fp32 into registers; ph3 (after the vmcnt that proves they landed)
// converts to bf16 and ds_writes 4x b128 into the next buffer -- producing
// the EXACT same LDS image global_load_lds produced before (linear dest,
// inverse-swizzled source element indices).  lgkmcnt(0) before ph3's closing
// barrier publishes the writes.  B staging stays global_load_lds.
//
// vmcnt ledger (steady state, at ph3 wait):
//   queue = [B_lds(t+1) x4  (issued ph2/ph3 of t-1),
//            A_reg(t+1) x8  (issued ph0/ph1 of t),
//            B_lds(t+2) x4  (issued ph2/ph3 of t)]
//   s_waitcnt vmcnt(4) -> leaves B(t+2) in flight; A-regs + B(t+1) landed.
// Prologue: queue = [A_reg(0) x8, B(0) x4, B(1) x4] -> vmcnt(4).
// ---------------------------------------------------------------------------

__device__ __forceinline__ void load_lds16(const void* g, void* l) {
    __builtin_amdgcn_global_load_lds(
        (const __attribute__((address_space(1))) unsigned int*)g,
        (__attribute__((address_space(3))) unsigned int*)l, 16, 0, 0);
}

#define MFMA_BF16 __builtin_amdgcn_mfma_f32_16x16x32_bf16

__global__ __launch_bounds__(512, 2) void gemm256_8ph(const float* __restrict__ X,
                                                      const __hip_bfloat16* __restrict__ B,
                                                      const float* __restrict__ bias,
                                                      float* __restrict__ C) {
    extern __shared__ __align__(16) char lds[];

    const int tid  = threadIdx.x;
    const int lane = tid & 63;
    const int wave = tid >> 6;

    // T1: XCD swizzle, 8x8 square chunk per XCD (512 wgs % 8 == 0, bijective).
    const int xcd = blockIdx.x & 7;
    const int w64 = blockIdx.x >> 3;               // 0..63 within XCD
    const int tm  = (xcd >> 1) * 8 + (w64 >> 3);   // 0..31 M-tiles
    const int tn  = (xcd & 1) * 8 + (w64 & 7);     // 0..15 N-tiles

    const __hip_bfloat16* Bb = B + (size_t)tn * 256 * IN_F;

    // Staging source mapping (inverse-swizzled, matches read-side XOR):
    // lane l supplies 16B(bf16): row (l>>2), elem ((l&3)*8) ^ (l>=32 ? 16 : 0).
    const int c0   = ((lane & 3) * 8) ^ ((lane >= 32) ? 16 : 0);
    const int arow = (wave >> 1) * 16 + (lane >> 2);     // 0..63
    const int acol = (wave & 1) * 32 + c0;               // 0..63

    // A: per-lane fp32 source base (same element indices as the bf16 path)
    const float* xA = X + (size_t)(tm * 256 + arow) * IN_F + acol;
    // B: per-lane bf16 source base for global_load_lds
    const size_t off0 = (size_t)arow * IN_F + acol;
    const __hip_bfloat16* qB0 = Bb + off0;
    const __hip_bfloat16* qB1 = Bb + (size_t)128 * IN_F + off0;

    // Swizzled ds_read lane offset within a 1 KiB subtile:
    // logical byte = (lane&15)*64 + (lane>>4)*16 ; swizzle XORs bit5 with bit9.
    const int flo = (lane & 15) * 64 + (((lane >> 4) * 16) ^ ((lane & 8) << 2));

    const int ah = wave >> 2;          // A half this wave reads (rows)
    const int bh = (wave >> 1) & 1;    // B half this wave reads (cols)
    const int bs = (wave & 1) * 4;     // B subtile-row base within half

    // Pre-folded LDS read bases per buffer: every read is base + literal.
    const char* aRd[2] = { lds + ah * 16384 + flo,
                           lds + 65536 + ah * 16384 + flo };
    const char* bRd[2] = { lds + 32768 + bh * 16384 + bs * 2048 + flo,
                           lds + 65536 + 32768 + bh * 16384 + bs * 2048 + flo };

    const int wv1024 = wave * 1024 + lane * 16;   // linear staging dest (bytes)

    f32x4 aR[4][2];    // fp32 A slice in flight: slot = row-block (0,64,128,192)

#define ALOAD(SLOT, TE) do {                                                \
        const float* p_ = xA + (size_t)(SLOT) * 64 * IN_F + (TE);           \
        aR[SLOT][0] = *(const f32x4*)(p_);                                  \
        aR[SLOT][1] = *(const f32x4*)(p_ + 4);                              \
    } while (0)

#define ASTORE(SLOT, NB) do {                                               \
        union { __hip_bfloat16 h[8]; uvec4 v; } pk_;                        \
        pk_.h[0] = __float2bfloat16(aR[SLOT][0].x);                         \
        pk_.h[1] = __float2bfloat16(aR[SLOT][0].y);                         \
        pk_.h[2] = __float2bfloat16(aR[SLOT][0].z);                         \
        pk_.h[3] = __float2bfloat16(aR[SLOT][0].w);                         \
        pk_.h[4] = __float2bfloat16(aR[SLOT][1].x);                         \
        pk_.h[5] = __float2bfloat16(aR[SLOT][1].y);                         \
        pk_.h[6] = __float2bfloat16(aR[SLOT][1].z);                         \
        pk_.h[7] = __float2bfloat16(aR[SLOT][1].w);                         \
        *(uvec4*)(lds + (NB) + (SLOT) * 8192 + wv1024) = pk_.v;             \
    } while (0)

#define STAGE2(ps, te, LO) do {                                             \
        const __hip_bfloat16* g_ = (ps) + (te);                             \
        load_lds16(g_,              lds + (LO) + wv1024);                   \
        load_lds16(g_ + 64 * IN_F,  lds + (LO) + 8192 + wv1024);            \
    } while (0)

    // ---- prologue: A(0) regs x8, B(0) x4, B(1) x4 ----
    ALOAD(0, 0); ALOAD(1, 0); ALOAD(2, 0); ALOAD(3, 0);
    STAGE2(qB0, 0,  32768);
    STAGE2(qB1, 0,  49152);
    STAGE2(qB0, 64, 65536 + 32768);
    STAGE2(qB1, 64, 65536 + 49152);
    asm volatile("s_waitcnt vmcnt(4)" ::: "memory");   // A-regs + B(0) landed
    ASTORE(0, 0); ASTORE(1, 0); ASTORE(2, 0); ASTORE(3, 0);
    asm volatile("s_waitcnt lgkmcnt(0)" ::: "memory"); // ds_writes visible
    __builtin_amdgcn_s_barrier();

    short8 aF[4][2], bAf[2][2], bBf[2][2];
    f32x4 acc[8][4] = {};

#define TILE(T, CBI) do {                                                          \
        const int t1e = (((T) + 1) & 63) << 6;   /* elem offset of tile T+1 */     \
        const int t2e = (((T) + 2) & 63) << 6;                                     \
        /* ---------- phase 0: quadrant (mh0, nh0) ---------- */                   \
        _Pragma("unroll")                                                          \
        for (int i = 0; i < 4; ++i)                                                \
            _Pragma("unroll")                                                      \
            for (int kk = 0; kk < 2; ++kk)                                         \
                aF[i][kk] = *(const short8*)(aRd[CBI] + (i * 2 + kk) * 1024);      \
        _Pragma("unroll")                                                          \
        for (int j = 0; j < 2; ++j)                                                \
            _Pragma("unroll")                                                      \
            for (int kk = 0; kk < 2; ++kk)                                         \
                bAf[j][kk] = *(const short8*)(bRd[CBI] + (j * 2 + kk) * 1024);     \
        ALOAD(0, t1e); ALOAD(1, t1e);                                              \
        __builtin_amdgcn_s_barrier();                                              \
        __builtin_amdgcn_s_setprio(1);                                             \
        _Pragma("unroll")                                                          \
        for (int i = 0; i < 4; ++i)                                                \
            _Pragma("unroll")                                                      \
            for (int j = 0; j < 2; ++j)                                            \
                _Pragma("unroll")                                                  \
                for (int kk = 0; kk < 2; ++kk)                                     \
                    acc[i][j] = MFMA_BF16(aF[i][kk], bAf[j][kk], acc[i][j], 0,0,0);\
        __builtin_amdgcn_s_setprio(0);                                             \
        __builtin_amdgcn_s_barrier();                                              \
        /* ---------- phase 1: quadrant (mh0, nh1) ---------- */                   \
        _Pragma("unroll")                                                          \
        for (int j = 0; j < 2; ++j)                                                \
            _Pragma("unroll")                                                      \
            for (int kk = 0; kk < 2; ++kk)                                         \
                bBf[j][kk] = *(const short8*)(bRd[CBI] + 4096 + (j*2+kk) * 1024);  \
        ALOAD(2, t1e); ALOAD(3, t1e);                                              \
        __builtin_amdgcn_s_barrier();                                              \
        __builtin_amdgcn_s_setprio(1);                                             \
        _Pragma("unroll")                                                          \
        for (int i = 0; i < 4; ++i)                                                \
            _Pragma("unroll")                                                      \
            for (int j = 0; j < 2; ++j)                                            \
                _Pragma("unroll")                                                  \
                for (int kk = 0; kk < 2; ++kk)                                     \
                    acc[i][2+j] = MFMA_BF16(aF[i][kk], bBf[j][kk], acc[i][2+j],0,0,0);\
        __builtin_amdgcn_s_setprio(0);                                             \
        __builtin_amdgcn_s_barrier();                                              \
        /* ---------- phase 2: quadrant (mh1, nh1) ---------- */                   \
        _Pragma("unroll")                                                          \
        for (int i = 0; i < 4; ++i)                                                \
            _Pragma("unroll")                                                      \
            for (int kk = 0; kk < 2; ++kk)                                         \
                aF[i][kk] = *(const short8*)(aRd[CBI] + 8192 + (i*2+kk) * 1024);   \
        STAGE2(qB0, t2e, (CBI) * 65536 + 32768);   /* dead after ph1 */            \
        __builtin_amdgcn_s_barrier();                                              \
        __builtin_amdgcn_s_setprio(1);                                             \
        _Pragma("unroll")                                                          \
        for (int i = 0; i < 4; ++i)                                                \
            _Pragma("unroll")                                                      \
            for (int j = 0; j < 2; ++j)                                            \
                _Pragma("unroll")                                                  \
                for (int kk = 0; kk < 2; ++kk)                                     \
                    acc[4+i][2+j] = MFMA_BF16(aF[i][kk], bBf[j][kk], acc[4+i][2+j],0,0,0);\
        __builtin_amdgcn_s_setprio(0);                                             \
        __builtin_amdgcn_s_barrier();                                              \
        /* ---------- phase 3: quadrant (mh1, nh0) ---------- */                   \
        STAGE2(qB1, t2e, (CBI) * 65536 + 49152);                                   \
        asm volatile("s_waitcnt vmcnt(4)" ::: "memory");  /* A-regs+B(t+1) in */   \
        __builtin_amdgcn_s_barrier();                     /* publish to all */     \
        __builtin_amdgcn_s_setprio(1);                                             \
        _Pragma("unroll")                                                          \
        for (int i = 0; i < 4; ++i)                                                \
            _Pragma("unroll")                                                      \
            for (int j = 0; j < 2; ++j)                                            \
                _Pragma("unroll")                                                  \
                for (int kk = 0; kk < 2; ++kk)                                     \
                    acc[4+i][j] = MFMA_BF16(aF[i][kk], bAf[j][kk], acc[4+i][j],0,0,0);\
        __builtin_amdgcn_s_setprio(0);                                             \
        /* cvt + ds_write A(t+1) into next buffer (region dead since t-1) */       \
        ASTORE(0, ((CBI)^1) * 65536); ASTORE(1, ((CBI)^1) * 65536);                \
        ASTORE(2, ((CBI)^1) * 65536); ASTORE(3, ((CBI)^1) * 65536);                \
        asm volatile("s_waitcnt lgkmcnt(0)" ::: "memory"); /* writes visible */    \
        __builtin_amdgcn_s_barrier();                                              \
    } while (0)

    for (int tt = 0; tt < 32; ++tt) {      // 2 K-tiles per iter: literal buffers
        TILE(2 * tt,     0);
        TILE(2 * tt + 1, 1);
    }
    asm volatile("s_waitcnt vmcnt(0)" ::: "memory");  // drain wrapped prefetches

    // ---- epilogue: D[row=(lane>>4)*4+r][col=lane&15] per 16x16 frag; +bias ----
    const int qd = lane >> 4;
    const int cl = lane & 15;
    const size_t m_base = (size_t)tm * 256 + (size_t)ah * 128;
    const int    n_base = tn * 256 + (wave & 3) * 64;
#pragma unroll
    for (int fn = 0; fn < 4; ++fn) {
        const int n = n_base + fn * 16 + cl;
        const float bv = bias[n];
#pragma unroll
        for (int fm = 0; fm < 8; ++fm) {
            const size_t m0 = m_base + fm * 16 + qd * 4;
#pragma unroll
            for (int r = 0; r < 4; ++r)
                __builtin_nontemporal_store(acc[fm][fn][r] + bv,
                                            &C[(m0 + r) * OUT_F + n]);
        }
    }
#undef STAGE2
#undef TILE
#undef ALOAD
#undef ASTORE
}

// ---------------------------------------------------------------------------
extern "C" void kernel_launch(void* const* d_in, const int* in_sizes, int n_in,
                              void* d_out, int out_size, void* d_ws, size_t ws_size,
                              hipStream_t stream) {
    const float* x    = (const float*)d_in[0];   // [4,2048,4096] fp32
    const int*   qc   = (const int*)d_in[1];     // [4096,4096] int32 codes
    const float* sc   = (const float*)d_in[2];   // [4096,64] fp32
    const float* bias = (const float*)d_in[3];   // [4096]
    const float* lA   = (const float*)d_in[4];   // [16,4096]
    const float* lB   = (const float*)d_in[5];   // [4096,16]
    float* out = (float*)d_out;                  // [4,2048,4096] fp32

    // workspace: W'_bf16 only (32 MB) -- xb intermediate eliminated
    __hip_bfloat16* wb = (__hip_bfloat16*)d_ws;

    // allow 128 KiB dynamic LDS for the 8-phase GEMM (host-side, capture-safe)
    static bool attr_done = false;
    if (!attr_done) {
        (void)hipFuncSetAttribute((const void*)gemm256_8ph,
                                  hipFuncAttributeMaxDynamicSharedMemorySize, 131072);
        attr_done = true;
    }

    dequant_lora<<<2048, 256, 0, stream>>>(qc, sc, lA, lB, wb);
    gemm256_8ph<<<dim3(512), dim3(512), 131072, stream>>>(x, wb, bias, out);
}